// Round 7
// baseline (413.261 us; speedup 1.0000x reference)
//
#include <hip/hip_runtime.h>

#define IN_DIM 40
#define HID 64
#define TSTEPS 500
#define CHAINS 16
#define ROWB 144           // LDS row stride: odd multiple of 16B -> conflict-free b128 reads

typedef _Float16 half8 __attribute__((ext_vector_type(8)));
typedef float    f32x4 __attribute__((ext_vector_type(4)));

__device__ __forceinline__ float sigmoid_fast(float x) {
    return __builtin_amdgcn_rcpf(1.0f + __expf(-x));
}

__device__ __forceinline__ float tanh_fast(float x) {
    float ax = fabsf(x);
    float e = __expf(-2.0f * ax);
    float r = (1.0f - e) * __builtin_amdgcn_rcpf(1.0f + e);
    return copysignf(r, x);
}

// LDS-visibility barrier: no vmcnt drain (in-flight global prefetch survives);
// memory-clobber fences stop LDS op motion, VALU may still cross.
__device__ __forceinline__ void block_sync_lds() {
    asm volatile("s_waitcnt lgkmcnt(0)" ::: "memory");
    __builtin_amdgcn_s_barrier();
    asm volatile("" ::: "memory");
}

// MFMA recurrence, 16 chains/block, 4 waves, gate-interleaved W rows.
// Z[256x16] = W'[256x128] . [h;x][128x16]; x-part B-frags come straight from global
// (prefetched 1 step ahead into registers) — only h round-trips through LDS.
// D layout (verified): col=lane&15 (chain), row=4*(lane>>4)+reg -> lane-local cell update.
__global__ __launch_bounds__(256, 1)
void lstm_mfma(const float* __restrict__ x,
               const float* __restrict__ W_ih,
               const float* __restrict__ W_hh,
               const float* __restrict__ b_ih,
               const float* __restrict__ b_hh,
               const float* __restrict__ fc1_w,
               const float* __restrict__ fc1_b,
               const float* __restrict__ fc2_w,
               const float* __restrict__ fc2_b,
               float* __restrict__ out)
{
    const int tid = threadIdx.x;
    const int w   = tid >> 6;        // wave id: m-tiles 4w..4w+3 (units 16w..16w+15)
    const int l   = tid & 63;
    const int lr  = l & 15;          // chain (B col / D col)
    const int lg  = l >> 4;          // k-group / D-row group
    const int blk = blockIdx.x;

    __shared__ __align__(16) unsigned char slab[2][CHAINS * ROWB];  // h only, 4608 B
    __shared__ float h32[CHAINS][HID];
    __shared__ float rl [CHAINS][HID];

    // ---- zero both slab parities (h0 = 0): 288 x uint4 ----
    {
        uint4 z{0, 0, 0, 0};
        uint4* zp = reinterpret_cast<uint4*>(slab);
        zp[tid] = z;
        if (tid < 32) zp[256 + tid] = z;
    }

    // ---- persistent A-fragments (gate-interleaved rows) + bias vectors ----
    half8 wfrag[4][4];
    f32x4 biasr[4];
    #pragma unroll
    for (int j = 0; j < 4; ++j) {
        const int jt   = 4 * w + j;
        const int unit = 4 * jt + (lr >> 2);
        const int gate = lr & 3;
        const int row  = gate * HID + unit;
        #pragma unroll
        for (int kt = 0; kt < 4; ++kt) {
            const int k0 = kt * 32 + lg * 8;
            float v[8];
            if (k0 < 64) {
                const float4* p = reinterpret_cast<const float4*>(W_hh + (size_t)row * HID + k0);
                float4 q0 = p[0], q1 = p[1];
                v[0]=q0.x; v[1]=q0.y; v[2]=q0.z; v[3]=q0.w;
                v[4]=q1.x; v[5]=q1.y; v[6]=q1.z; v[7]=q1.w;
            } else if (k0 < 104) {
                const float4* p = reinterpret_cast<const float4*>(W_ih + (size_t)row * IN_DIM + (k0 - 64));
                float4 q0 = p[0], q1 = p[1];
                v[0]=q0.x; v[1]=q0.y; v[2]=q0.z; v[3]=q0.w;
                v[4]=q1.x; v[5]=q1.y; v[6]=q1.z; v[7]=q1.w;
            } else {
                #pragma unroll
                for (int e = 0; e < 8; ++e) v[e] = 0.0f;
            }
            half8 hv;
            #pragma unroll
            for (int e = 0; e < 8; ++e) hv[e] = (_Float16)v[e];
            wfrag[j][kt] = hv;
        }
        const int ud = 4 * jt + lg;   // D rows 4lg+r -> gate r of unit ud
        biasr[j] = f32x4{ b_ih[0 * HID + ud] + b_hh[0 * HID + ud],
                          b_ih[1 * HID + ud] + b_hh[1 * HID + ud],
                          b_ih[2 * HID + ud] + b_hh[2 * HID + ud],
                          b_ih[3 * HID + ud] + b_hh[3 * HID + ud] };
    }

    // ---- per-lane x addresses: chain lr, elems lg*8..+7 (kt=2) and 32..39 (kt=3) ----
    const float* xrow = x + ((size_t)(blk * CHAINS + lr) * TSTEPS) * IN_DIM;
    const float* xg2  = xrow + lg * 8;
    const float* xg3  = xrow + 32;    // only lg==0's A-frag is nonzero for kt=3

    float4 a0, a1, a2, a3, b0, b1, b2, b3;
    a0 = *reinterpret_cast<const float4*>(xg2);       // x_0
    a1 = *reinterpret_cast<const float4*>(xg2 + 4);
    a2 = *reinterpret_cast<const float4*>(xg3);
    a3 = *reinterpret_cast<const float4*>(xg3 + 4);

    __syncthreads();   // one-time full drain (slab zero visible)

    float cs[4] = {0.f, 0.f, 0.f, 0.f};
    float hreg[4];

    auto step = [&](int t, int par,
                    const float4& c0, const float4& c1, const float4& c2, const float4& c3,
                    float4& n0, float4& n1, float4& n2, float4& n3) {
        const bool lastt = (t == TSTEPS - 1);
        // h B-frags from slab[par]: issue first (latency hidden by x work below)
        const unsigned char* sp = &slab[par][0] + lr * ROWB + lg * 16;
        uint4 q0 = *reinterpret_cast<const uint4*>(sp);
        uint4 q1 = *reinterpret_cast<const uint4*>(sp + 64);
        // prefetch x_{t+1} (in-flight across the barrier; used next step)
        const size_t toff = (size_t)(lastt ? t : t + 1) * IN_DIM;
        n0 = *reinterpret_cast<const float4*>(xg2 + toff);
        n1 = *reinterpret_cast<const float4*>(xg2 + toff + 4);
        n2 = *reinterpret_cast<const float4*>(xg3 + toff);
        n3 = *reinterpret_cast<const float4*>(xg3 + toff + 4);
        // convert this step's x to B-frags (register-only)
        half8 xf2 = { (_Float16)c0.x, (_Float16)c0.y, (_Float16)c0.z, (_Float16)c0.w,
                      (_Float16)c1.x, (_Float16)c1.y, (_Float16)c1.z, (_Float16)c1.w };
        half8 xf3 = { (_Float16)c2.x, (_Float16)c2.y, (_Float16)c2.z, (_Float16)c2.w,
                      (_Float16)c3.x, (_Float16)c3.y, (_Float16)c3.z, (_Float16)c3.w };
        half8 bf0 = __builtin_bit_cast(half8, q0);
        half8 bf1 = __builtin_bit_cast(half8, q1);
        #pragma unroll
        for (int j = 0; j < 4; ++j) {
            f32x4 acc = biasr[j];
            // x-part first: operands register-ready, runs under h ds_read latency
            acc = __builtin_amdgcn_mfma_f32_16x16x32_f16(wfrag[j][2], xf2, acc, 0, 0, 0);
            acc = __builtin_amdgcn_mfma_f32_16x16x32_f16(wfrag[j][3], xf3, acc, 0, 0, 0);
            acc = __builtin_amdgcn_mfma_f32_16x16x32_f16(wfrag[j][0], bf0, acc, 0, 0, 0);
            acc = __builtin_amdgcn_mfma_f32_16x16x32_f16(wfrag[j][1], bf1, acc, 0, 0, 0);
            // acc = {z_i, z_f, z_g, z_o} of (unit 4*(4w+j)+lg, chain lr)
            float iv = sigmoid_fast(acc[0]);
            float fv = sigmoid_fast(acc[1]);
            float gv = tanh_fast(acc[2]);
            float ov = sigmoid_fast(acc[3]);
            cs[j]   = fmaf(fv, cs[j], iv * gv);
            hreg[j] = ov * tanh_fast(cs[j]);
        }
        if (lastt) {
            #pragma unroll
            for (int j = 0; j < 4; ++j)
                h32[lr][4 * (4 * w + j) + lg] = hreg[j];
        } else {
            unsigned char* dp = &slab[par ^ 1][0] + lr * ROWB;
            #pragma unroll
            for (int j = 0; j < 4; ++j) {
                const int u = 4 * (4 * w + j) + lg;
                _Float16 hf = (_Float16)hreg[j];
                *reinterpret_cast<unsigned short*>(dp + u * 2) =
                    __builtin_bit_cast(unsigned short, hf);
            }
        }
        block_sync_lds();   // the only per-step barrier (lgkmcnt only)
    };

    #pragma unroll 1
    for (int t = 0; t < TSTEPS; t += 2) {
        step(t,     0, a0, a1, a2, a3, b0, b1, b2, b3);
        step(t + 1, 1, b0, b1, b2, b3, a0, a1, a2, a3);
    }

    // ---- epilogue: fc1 + relu (wave w -> chains 4w..4w+3), then fc2 ----
    {
        float4 wrow[16];
        const float4* fwp = reinterpret_cast<const float4*>(fc1_w + (size_t)l * HID);
        #pragma unroll
        for (int q = 0; q < 16; ++q) wrow[q] = fwp[q];
        const float b1 = fc1_b[l];
        #pragma unroll
        for (int cc = 0; cc < 4; ++cc) {
            const int chain = 4 * w + cc;
            float acc = b1;
            #pragma unroll
            for (int q = 0; q < 16; ++q) {
                float4 hv = reinterpret_cast<const float4*>(&h32[chain][0])[q];
                acc = fmaf(wrow[q].x, hv.x, acc);
                acc = fmaf(wrow[q].y, hv.y, acc);
                acc = fmaf(wrow[q].z, hv.z, acc);
                acc = fmaf(wrow[q].w, hv.w, acc);
            }
            rl[chain][l] = fmaxf(acc, 0.0f);
        }
    }
    __syncthreads();
    if (tid < 32) {
        const int c = tid >> 1;
        const int o = tid & 1;
        float acc = fc2_b[o];
        for (int k = 0; k < HID; ++k)
            acc = fmaf(fc2_w[o * HID + k], rl[c][k], acc);
        out[(size_t)(blk * CHAINS + c) * 2 + o] = acc;
    }
}

extern "C" void kernel_launch(void* const* d_in, const int* in_sizes, int n_in,
                              void* d_out, int out_size, void* d_ws, size_t ws_size,
                              hipStream_t stream) {
    const float* x     = (const float*)d_in[0];
    const float* W_ih  = (const float*)d_in[1];
    const float* W_hh  = (const float*)d_in[2];
    const float* b_ih  = (const float*)d_in[3];
    const float* b_hh  = (const float*)d_in[4];
    const float* fc1_w = (const float*)d_in[5];
    const float* fc1_b = (const float*)d_in[6];
    const float* fc2_w = (const float*)d_in[7];
    const float* fc2_b = (const float*)d_in[8];
    float* out = (float*)d_out;

    const int B = in_sizes[0] / (TSTEPS * IN_DIM);   // 1024
    lstm_mfma<<<B / CHAINS, 256, 0, stream>>>(x, W_ih, W_hh, b_ih, b_hh,
                                              fc1_w, fc1_b, fc2_w, fc2_b, out);
}

// Round 8
// 300.307 us; speedup vs baseline: 1.3761x; 1.3761x over previous
//
#include <hip/hip_runtime.h>

#define IN_DIM 40
#define HID 64
#define TSTEPS 500
#define CHAINS 16

typedef _Float16 half8 __attribute__((ext_vector_type(8)));
typedef float    f32x4 __attribute__((ext_vector_type(4)));

__device__ __forceinline__ float sigmoid_fast(float x) {
    return __builtin_amdgcn_rcpf(1.0f + __expf(-x));
}

__device__ __forceinline__ float tanh_fast(float x) {
    float ax = fabsf(x);
    float e = __expf(-2.0f * ax);
    float r = (1.0f - e) * __builtin_amdgcn_rcpf(1.0f + e);
    return copysignf(r, x);
}

// LDS-visibility barrier: no vmcnt drain (in-flight global prefetch survives).
__device__ __forceinline__ void block_sync_lds() {
    asm volatile("s_waitcnt lgkmcnt(0)" ::: "memory");
    __builtin_amdgcn_s_barrier();
    asm volatile("" ::: "memory");
}

// MFMA recurrence, 16 chains/block, 4 waves, gate-interleaved W rows.
// Step-t critical chain is h-only: ds_read h -> 2 MFMA -> act -> h write -> barrier.
// The x-part (bias + Wx.x_{t+1}) is precomputed DURING step t into xacc (2 MFMA/tile),
// placed after the acts so its vmcnt wait sits in dead time.
// D layout (verified): col=lane&15 (chain), row=4*(lane>>4)+reg -> lane-local cell.
__global__ __launch_bounds__(256, 1)
void lstm_mfma(const float* __restrict__ x,
               const float* __restrict__ W_ih,
               const float* __restrict__ W_hh,
               const float* __restrict__ b_ih,
               const float* __restrict__ b_hh,
               const float* __restrict__ fc1_w,
               const float* __restrict__ fc1_b,
               const float* __restrict__ fc2_w,
               const float* __restrict__ fc2_b,
               float* __restrict__ out)
{
    const int tid = threadIdx.x;
    const int w   = tid >> 6;        // wave id: m-tiles 4w..4w+3 (units 16w..16w+15)
    const int l   = tid & 63;
    const int lr  = l & 15;          // chain (B col / D col)
    const int lg  = l >> 4;          // k-group / D-row group
    const int blk = blockIdx.x;
    const int sw  = (lr & 7) << 4;   // per-row 16B-group XOR swizzle

    __shared__ __align__(16) unsigned short slab[2][CHAINS][HID];   // h only, 4 KB
    __shared__ float h32[CHAINS][HID];
    __shared__ float rl [CHAINS][HID];

    // ---- zero slab[0] (h0 = 0): 2048 B = 128 x uint4 ----
    if (tid < 128) reinterpret_cast<uint4*>(slab)[tid] = uint4{0, 0, 0, 0};

    // ---- persistent A-fragments (gate-interleaved rows) + bias vectors ----
    half8 wfrag[4][4];
    f32x4 biasr[4];
    #pragma unroll
    for (int j = 0; j < 4; ++j) {
        const int jt   = 4 * w + j;
        const int unit = 4 * jt + (lr >> 2);
        const int gate = lr & 3;
        const int row  = gate * HID + unit;
        #pragma unroll
        for (int kt = 0; kt < 4; ++kt) {
            const int k0 = kt * 32 + lg * 8;
            float v[8];
            if (k0 < 64) {
                const float4* p = reinterpret_cast<const float4*>(W_hh + (size_t)row * HID + k0);
                float4 q0 = p[0], q1 = p[1];
                v[0]=q0.x; v[1]=q0.y; v[2]=q0.z; v[3]=q0.w;
                v[4]=q1.x; v[5]=q1.y; v[6]=q1.z; v[7]=q1.w;
            } else if (k0 < 104) {
                const float4* p = reinterpret_cast<const float4*>(W_ih + (size_t)row * IN_DIM + (k0 - 64));
                float4 q0 = p[0], q1 = p[1];
                v[0]=q0.x; v[1]=q0.y; v[2]=q0.z; v[3]=q0.w;
                v[4]=q1.x; v[5]=q1.y; v[6]=q1.z; v[7]=q1.w;
            } else {
                #pragma unroll
                for (int e = 0; e < 8; ++e) v[e] = 0.0f;
            }
            half8 hv;
            #pragma unroll
            for (int e = 0; e < 8; ++e) hv[e] = (_Float16)v[e];
            wfrag[j][kt] = hv;
        }
        const int ud = 4 * jt + lg;
        biasr[j] = f32x4{ b_ih[0 * HID + ud] + b_hh[0 * HID + ud],
                          b_ih[1 * HID + ud] + b_hh[1 * HID + ud],
                          b_ih[2 * HID + ud] + b_hh[2 * HID + ud],
                          b_ih[3 * HID + ud] + b_hh[3 * HID + ud] };
    }

    // ---- per-lane x addresses: chain lr; kt=2 elems lg*8..+7, kt=3 elems 32..39 ----
    const float* xrow = x + ((size_t)(blk * CHAINS + lr) * TSTEPS) * IN_DIM;
    const float* xg2  = xrow + lg * 8;
    const float* xg3  = xrow + 32;      // kt=3: only lg==0's A-frag nonzero (pad zeroed)

    // ---- prologue: xacc for t=0 from x_0; prefetch x_1 ----
    f32x4 xaccA[4], xaccB[4];
    {
        float4 p0 = *reinterpret_cast<const float4*>(xg2);
        float4 p1 = *reinterpret_cast<const float4*>(xg2 + 4);
        float4 p2 = *reinterpret_cast<const float4*>(xg3);
        float4 p3 = *reinterpret_cast<const float4*>(xg3 + 4);
        half8 xf2 = { (_Float16)p0.x, (_Float16)p0.y, (_Float16)p0.z, (_Float16)p0.w,
                      (_Float16)p1.x, (_Float16)p1.y, (_Float16)p1.z, (_Float16)p1.w };
        half8 xf3 = { (_Float16)p2.x, (_Float16)p2.y, (_Float16)p2.z, (_Float16)p2.w,
                      (_Float16)p3.x, (_Float16)p3.y, (_Float16)p3.z, (_Float16)p3.w };
        #pragma unroll
        for (int j = 0; j < 4; ++j) {
            f32x4 a = biasr[j];
            a = __builtin_amdgcn_mfma_f32_16x16x32_f16(wfrag[j][2], xf2, a, 0, 0, 0);
            a = __builtin_amdgcn_mfma_f32_16x16x32_f16(wfrag[j][3], xf3, a, 0, 0, 0);
            xaccA[j] = a;
        }
    }
    float4 rA0 = *reinterpret_cast<const float4*>(xg2 + IN_DIM);
    float4 rA1 = *reinterpret_cast<const float4*>(xg2 + IN_DIM + 4);
    float4 rA2 = *reinterpret_cast<const float4*>(xg3 + IN_DIM);
    float4 rA3 = *reinterpret_cast<const float4*>(xg3 + IN_DIM + 4);
    float4 rB0, rB1, rB2, rB3;

    __syncthreads();   // one-time full drain (slab[0] zero visible)

    float cs[4] = {0.f, 0.f, 0.f, 0.f};
    float hreg[4];

    auto step = [&](int t, int par, f32x4 (&xacc)[4], f32x4 (&xnxt)[4],
                    const float4& c0, const float4& c1, const float4& c2, const float4& c3,
                    float4& n0, float4& n1, float4& n2, float4& n3) {
        const bool lastt = (t == TSTEPS - 1);
        const char* sb = reinterpret_cast<const char*>(slab) + par * 2048 + lr * 128;
        // 1. h B-frags (swizzled; the only LDS on the critical path)
        uint4 q0 = *reinterpret_cast<const uint4*>(sb + ((lg * 16) ^ sw));
        uint4 q1 = *reinterpret_cast<const uint4*>(sb + ((64 + lg * 16) ^ sw));
        // 2. issue x_{t+2} prefetch (used next step, off-path)
        {
            const size_t toff = (size_t)((t + 2 < TSTEPS) ? t + 2 : TSTEPS - 1) * IN_DIM;
            n0 = *reinterpret_cast<const float4*>(xg2 + toff);
            n1 = *reinterpret_cast<const float4*>(xg2 + toff + 4);
            n2 = *reinterpret_cast<const float4*>(xg3 + toff);
            n3 = *reinterpret_cast<const float4*>(xg3 + toff + 4);
        }
        // 3. h MFMAs: depth-2 chain on top of precomputed xacc
        half8 bf0 = __builtin_bit_cast(half8, q0);
        half8 bf1 = __builtin_bit_cast(half8, q1);
        f32x4 acc[4];
        #pragma unroll
        for (int j = 0; j < 4; ++j) {
            f32x4 a = xacc[j];
            a = __builtin_amdgcn_mfma_f32_16x16x32_f16(wfrag[j][0], bf0, a, 0, 0, 0);
            a = __builtin_amdgcn_mfma_f32_16x16x32_f16(wfrag[j][1], bf1, a, 0, 0, 0);
            acc[j] = a;
        }
        // 4. activations + cell state + h publish
        char* db = reinterpret_cast<char*>(slab) + (par ^ 1) * 2048 + lr * 128;
        #pragma unroll
        for (int j = 0; j < 4; ++j) {
            float iv = sigmoid_fast(acc[j][0]);
            float fv = sigmoid_fast(acc[j][1]);
            float gv = tanh_fast(acc[j][2]);
            float ov = sigmoid_fast(acc[j][3]);
            cs[j]   = fmaf(fv, cs[j], iv * gv);
            hreg[j] = ov * tanh_fast(cs[j]);
            const int u = 4 * (4 * w + j) + lg;
            if (lastt) {
                h32[lr][u] = hreg[j];
            } else {
                _Float16 hf = (_Float16)hreg[j];
                *reinterpret_cast<unsigned short*>(db + ((u * 2) ^ sw)) =
                    __builtin_bit_cast(unsigned short, hf);
            }
        }
        // 5. precompute next step's x-part (vmcnt wait lands HERE, behind the acts)
        {
            half8 xf2 = { (_Float16)c0.x, (_Float16)c0.y, (_Float16)c0.z, (_Float16)c0.w,
                          (_Float16)c1.x, (_Float16)c1.y, (_Float16)c1.z, (_Float16)c1.w };
            half8 xf3 = { (_Float16)c2.x, (_Float16)c2.y, (_Float16)c2.z, (_Float16)c2.w,
                          (_Float16)c3.x, (_Float16)c3.y, (_Float16)c3.z, (_Float16)c3.w };
            #pragma unroll
            for (int j = 0; j < 4; ++j) {
                f32x4 a = biasr[j];
                a = __builtin_amdgcn_mfma_f32_16x16x32_f16(wfrag[j][2], xf2, a, 0, 0, 0);
                a = __builtin_amdgcn_mfma_f32_16x16x32_f16(wfrag[j][3], xf3, a, 0, 0, 0);
                xnxt[j] = a;
            }
        }
        // 6. the only per-step barrier (lgkmcnt only; global prefetch stays in flight)
        block_sync_lds();
    };

    #pragma unroll 1
    for (int t = 0; t < TSTEPS; t += 2) {
        step(t,     0, xaccA, xaccB, rA0, rA1, rA2, rA3, rB0, rB1, rB2, rB3);
        step(t + 1, 1, xaccB, xaccA, rB0, rB1, rB2, rB3, rA0, rA1, rA2, rA3);
    }

    // ---- epilogue: fc1 + relu (wave w -> chains 4w..4w+3), then fc2 ----
    {
        float4 wrow[16];
        const float4* fwp = reinterpret_cast<const float4*>(fc1_w + (size_t)l * HID);
        #pragma unroll
        for (int q = 0; q < 16; ++q) wrow[q] = fwp[q];
        const float b1 = fc1_b[l];
        #pragma unroll
        for (int cc = 0; cc < 4; ++cc) {
            const int chain = 4 * w + cc;
            float acc = b1;
            #pragma unroll
            for (int q = 0; q < 16; ++q) {
                float4 hv = reinterpret_cast<const float4*>(&h32[chain][0])[q];
                acc = fmaf(wrow[q].x, hv.x, acc);
                acc = fmaf(wrow[q].y, hv.y, acc);
                acc = fmaf(wrow[q].z, hv.z, acc);
                acc = fmaf(wrow[q].w, hv.w, acc);
            }
            rl[chain][l] = fmaxf(acc, 0.0f);
        }
    }
    __syncthreads();
    if (tid < 32) {
        const int c = tid >> 1;
        const int o = tid & 1;
        float acc = fc2_b[o];
        for (int k = 0; k < HID; ++k)
            acc = fmaf(fc2_w[o * HID + k], rl[c][k], acc);
        out[(size_t)(blk * CHAINS + c) * 2 + o] = acc;
    }
}

extern "C" void kernel_launch(void* const* d_in, const int* in_sizes, int n_in,
                              void* d_out, int out_size, void* d_ws, size_t ws_size,
                              hipStream_t stream) {
    const float* x     = (const float*)d_in[0];
    const float* W_ih  = (const float*)d_in[1];
    const float* W_hh  = (const float*)d_in[2];
    const float* b_ih  = (const float*)d_in[3];
    const float* b_hh  = (const float*)d_in[4];
    const float* fc1_w = (const float*)d_in[5];
    const float* fc1_b = (const float*)d_in[6];
    const float* fc2_w = (const float*)d_in[7];
    const float* fc2_b = (const float*)d_in[8];
    float* out = (float*)d_out;

    const int B = in_sizes[0] / (TSTEPS * IN_DIM);   // 1024
    lstm_mfma<<<B / CHAINS, 256, 0, stream>>>(x, W_ih, W_hh, b_ih, b_hh,
                                              fc1_w, fc1_b, fc2_w, fc2_b, out);
}

// Round 9
// 253.732 us; speedup vs baseline: 1.6287x; 1.1836x over previous
//
#include <hip/hip_runtime.h>

#define IN_DIM 40
#define HID 64
#define TSTEPS 500
#define NCH 4              // chains per block (replicated x4 in MFMA columns)
#define ROWB 144           // slab row stride in bytes: odd multiple of 16B -> conflict-free
#define SLABP (16 * ROWB)  // bytes per parity: 16 replica rows

typedef _Float16 half8 __attribute__((ext_vector_type(8)));
typedef float    f32x4 __attribute__((ext_vector_type(4)));

__device__ __forceinline__ float sigmoid_fast(float x) {
    return __builtin_amdgcn_rcpf(1.0f + __expf(-x));
}

__device__ __forceinline__ float tanh_fast(float x) {
    float ax = fabsf(x);
    float e = __expf(-2.0f * ax);
    float r = (1.0f - e) * __builtin_amdgcn_rcpf(1.0f + e);
    return copysignf(r, x);
}

// LDS-visibility barrier: no vmcnt drain (in-flight global prefetch survives).
__device__ __forceinline__ void block_sync_lds() {
    asm volatile("s_waitcnt lgkmcnt(0)" ::: "memory");
    __builtin_amdgcn_s_barrier();
    asm volatile("" ::: "memory");
}

// MFMA recurrence, 4 chains/block (256 blocks = full chip), 4 waves.
// B columns replicate chain (col&3) -> D replicated -> each lane owns ONE real cell
// (jj = lr>>2 selects which m-tile's acc), so act/trans work is 1 cell/thread:
// 10 quarter-rate trans ops per wave per step instead of 40.
// h slab: chain h replicated in 16 rows @144B stride (row r holds chain r&3) ->
// 64 distinct ds_read_b128 addresses spread 8-per-bank-group = conflict-free.
__global__ __launch_bounds__(256, 1)
void lstm_mfma(const float* __restrict__ x,
               const float* __restrict__ W_ih,
               const float* __restrict__ W_hh,
               const float* __restrict__ b_ih,
               const float* __restrict__ b_hh,
               const float* __restrict__ fc1_w,
               const float* __restrict__ fc1_b,
               const float* __restrict__ fc2_w,
               const float* __restrict__ fc2_b,
               float* __restrict__ out)
{
    const int tid = threadIdx.x;
    const int w   = tid >> 6;        // wave id: m-tiles 4w..4w+3 (units 16w..16w+15)
    const int l   = tid & 63;
    const int lr  = l & 15;          // B/D column; chain = lr&3, replica = lr>>2
    const int lg  = l >> 4;          // k-group / D-row group
    const int ch  = lr & 3;          // this lane's chain
    const int jj  = lr >> 2;         // this lane's owned m-tile (cell select)
    const int blk = blockIdx.x;

    __shared__ __align__(16) unsigned char slab[2 * SLABP];   // 4608 B, parity dbuf
    __shared__ float h32[NCH][HID];
    __shared__ float rl [NCH][HID];

    // ---- zero slab parity 0 (h0 = 0): 2304 B = 144 x uint4 ----
    if (tid < SLABP / 16) reinterpret_cast<uint4*>(slab)[tid] = uint4{0, 0, 0, 0};

    // ---- persistent A-fragments (gate-interleaved rows) + bias vectors ----
    half8 wfrag[4][4];
    f32x4 biasr[4];
    #pragma unroll
    for (int j = 0; j < 4; ++j) {
        const int jt   = 4 * w + j;
        const int unit = 4 * jt + (lr >> 2);
        const int gate = lr & 3;
        const int row  = gate * HID + unit;
        #pragma unroll
        for (int kt = 0; kt < 4; ++kt) {
            const int k0 = kt * 32 + lg * 8;
            float v[8];
            if (k0 < 64) {
                const float4* p = reinterpret_cast<const float4*>(W_hh + (size_t)row * HID + k0);
                float4 q0 = p[0], q1 = p[1];
                v[0]=q0.x; v[1]=q0.y; v[2]=q0.z; v[3]=q0.w;
                v[4]=q1.x; v[5]=q1.y; v[6]=q1.z; v[7]=q1.w;
            } else if (k0 < 104) {
                const float4* p = reinterpret_cast<const float4*>(W_ih + (size_t)row * IN_DIM + (k0 - 64));
                float4 q0 = p[0], q1 = p[1];
                v[0]=q0.x; v[1]=q0.y; v[2]=q0.z; v[3]=q0.w;
                v[4]=q1.x; v[5]=q1.y; v[6]=q1.z; v[7]=q1.w;
            } else {
                #pragma unroll
                for (int e = 0; e < 8; ++e) v[e] = 0.0f;
            }
            half8 hv;
            #pragma unroll
            for (int e = 0; e < 8; ++e) hv[e] = (_Float16)v[e];
            wfrag[j][kt] = hv;
        }
        const int ud = 4 * jt + lg;
        biasr[j] = f32x4{ b_ih[0 * HID + ud] + b_hh[0 * HID + ud],
                          b_ih[1 * HID + ud] + b_hh[1 * HID + ud],
                          b_ih[2 * HID + ud] + b_hh[2 * HID + ud],
                          b_ih[3 * HID + ud] + b_hh[3 * HID + ud] };
    }

    // ---- per-lane x addresses: chain ch; kt=2 elems lg*8..+7, kt=3 elems 32..39 ----
    const float* xrow = x + ((size_t)(blk * NCH + ch) * TSTEPS) * IN_DIM;
    const float* xg2  = xrow + lg * 8;
    const float* xg3  = xrow + 32;      // kt=3: only lg==0's A-frag nonzero (pad zeroed)

    // ---- prologue: xacc for t=0 from x_0; prefetch x_1 ----
    f32x4 xaccA[4], xaccB[4];
    {
        float4 p0 = *reinterpret_cast<const float4*>(xg2);
        float4 p1 = *reinterpret_cast<const float4*>(xg2 + 4);
        float4 p2 = *reinterpret_cast<const float4*>(xg3);
        float4 p3 = *reinterpret_cast<const float4*>(xg3 + 4);
        half8 xf2 = { (_Float16)p0.x, (_Float16)p0.y, (_Float16)p0.z, (_Float16)p0.w,
                      (_Float16)p1.x, (_Float16)p1.y, (_Float16)p1.z, (_Float16)p1.w };
        half8 xf3 = { (_Float16)p2.x, (_Float16)p2.y, (_Float16)p2.z, (_Float16)p2.w,
                      (_Float16)p3.x, (_Float16)p3.y, (_Float16)p3.z, (_Float16)p3.w };
        #pragma unroll
        for (int j = 0; j < 4; ++j) {
            f32x4 a = biasr[j];
            a = __builtin_amdgcn_mfma_f32_16x16x32_f16(wfrag[j][2], xf2, a, 0, 0, 0);
            a = __builtin_amdgcn_mfma_f32_16x16x32_f16(wfrag[j][3], xf3, a, 0, 0, 0);
            xaccA[j] = a;
        }
    }
    float4 rA0 = *reinterpret_cast<const float4*>(xg2 + IN_DIM);
    float4 rA1 = *reinterpret_cast<const float4*>(xg2 + IN_DIM + 4);
    float4 rA2 = *reinterpret_cast<const float4*>(xg3 + IN_DIM);
    float4 rA3 = *reinterpret_cast<const float4*>(xg3 + IN_DIM + 4);
    float4 rB0, rB1, rB2, rB3;

    __syncthreads();   // one-time full drain (slab zero visible)

    float cs = 0.0f;   // ONE cell per thread: (chain ch, unit 16w + 4*jj + lg)
    const int uown = 16 * w + 4 * jj + lg;

    auto step = [&](int t, int par, f32x4 (&xacc)[4], f32x4 (&xnxt)[4],
                    const float4& c0, const float4& c1, const float4& c2, const float4& c3,
                    float4& n0, float4& n1, float4& n2, float4& n3) {
        const bool lastt = (t == TSTEPS - 1);
        // 1. h B-frags: row lr (holds chain lr&3), conflict-free via 144B stride
        const unsigned char* sb = slab + par * SLABP + lr * ROWB;
        uint4 q0 = *reinterpret_cast<const uint4*>(sb + lg * 16);
        uint4 q1 = *reinterpret_cast<const uint4*>(sb + 64 + lg * 16);
        // 2. issue x_{t+2} prefetch (used next step, off-path)
        {
            const size_t toff = (size_t)((t + 2 < TSTEPS) ? t + 2 : TSTEPS - 1) * IN_DIM;
            n0 = *reinterpret_cast<const float4*>(xg2 + toff);
            n1 = *reinterpret_cast<const float4*>(xg2 + toff + 4);
            n2 = *reinterpret_cast<const float4*>(xg3 + toff);
            n3 = *reinterpret_cast<const float4*>(xg3 + toff + 4);
        }
        // 3. h MFMAs: depth-2 chain on top of precomputed xacc
        half8 bf0 = __builtin_bit_cast(half8, q0);
        half8 bf1 = __builtin_bit_cast(half8, q1);
        f32x4 acc[4];
        #pragma unroll
        for (int j = 0; j < 4; ++j) {
            f32x4 a = xacc[j];
            a = __builtin_amdgcn_mfma_f32_16x16x32_f16(wfrag[j][0], bf0, a, 0, 0, 0);
            a = __builtin_amdgcn_mfma_f32_16x16x32_f16(wfrag[j][1], bf1, a, 0, 0, 0);
            acc[j] = a;
        }
        // 4. select this lane's cell (jj) without runtime indexing, then acts
        float z0, z1, z2, z3;
        {
            float t01, t23;
            t01 = (jj & 1) ? acc[1][0] : acc[0][0];
            t23 = (jj & 1) ? acc[3][0] : acc[2][0];
            z0  = (jj & 2) ? t23 : t01;
            t01 = (jj & 1) ? acc[1][1] : acc[0][1];
            t23 = (jj & 1) ? acc[3][1] : acc[2][1];
            z1  = (jj & 2) ? t23 : t01;
            t01 = (jj & 1) ? acc[1][2] : acc[0][2];
            t23 = (jj & 1) ? acc[3][2] : acc[2][2];
            z2  = (jj & 2) ? t23 : t01;
            t01 = (jj & 1) ? acc[1][3] : acc[0][3];
            t23 = (jj & 1) ? acc[3][3] : acc[2][3];
            z3  = (jj & 2) ? t23 : t01;
        }
        float iv = sigmoid_fast(z0);
        float fv = sigmoid_fast(z1);
        float gv = tanh_fast(z2);
        float ov = sigmoid_fast(z3);
        cs = fmaf(fv, cs, iv * gv);
        float h = ov * tanh_fast(cs);
        // 5. publish h to the 4 replica rows of chain ch (next parity)
        if (lastt) {
            h32[ch][uown] = h;
        } else {
            unsigned char* db = slab + (par ^ 1) * SLABP + uown * 2;
            _Float16 hf = (_Float16)h;
            unsigned short hb = __builtin_bit_cast(unsigned short, hf);
            *reinterpret_cast<unsigned short*>(db + (ch     ) * ROWB) = hb;
            *reinterpret_cast<unsigned short*>(db + (ch +  4) * ROWB) = hb;
            *reinterpret_cast<unsigned short*>(db + (ch +  8) * ROWB) = hb;
            *reinterpret_cast<unsigned short*>(db + (ch + 12) * ROWB) = hb;
        }
        // 6. precompute next step's x-part (vmcnt wait lands here, behind the acts)
        {
            half8 xf2 = { (_Float16)c0.x, (_Float16)c0.y, (_Float16)c0.z, (_Float16)c0.w,
                          (_Float16)c1.x, (_Float16)c1.y, (_Float16)c1.z, (_Float16)c1.w };
            half8 xf3 = { (_Float16)c2.x, (_Float16)c2.y, (_Float16)c2.z, (_Float16)c2.w,
                          (_Float16)c3.x, (_Float16)c3.y, (_Float16)c3.z, (_Float16)c3.w };
            #pragma unroll
            for (int j = 0; j < 4; ++j) {
                f32x4 a = biasr[j];
                a = __builtin_amdgcn_mfma_f32_16x16x32_f16(wfrag[j][2], xf2, a, 0, 0, 0);
                a = __builtin_amdgcn_mfma_f32_16x16x32_f16(wfrag[j][3], xf3, a, 0, 0, 0);
                xnxt[j] = a;
            }
        }
        // 7. the only per-step barrier (lgkmcnt only; global prefetch stays in flight)
        block_sync_lds();
    };

    #pragma unroll 1
    for (int t = 0; t < TSTEPS; t += 2) {
        step(t,     0, xaccA, xaccB, rA0, rA1, rA2, rA3, rB0, rB1, rB2, rB3);
        step(t + 1, 1, xaccB, xaccA, rB0, rB1, rB2, rB3, rA0, rA1, rA2, rA3);
    }

    // ---- epilogue: fc1 + relu (wave w -> chain w), then fc2 ----
    {
        float acc = fc1_b[l];
        const float4* fwp = reinterpret_cast<const float4*>(fc1_w + (size_t)l * HID);
        #pragma unroll
        for (int q = 0; q < 16; ++q) {
            float4 wv = fwp[q];
            float4 hv = reinterpret_cast<const float4*>(&h32[w][0])[q];
            acc = fmaf(wv.x, hv.x, acc);
            acc = fmaf(wv.y, hv.y, acc);
            acc = fmaf(wv.z, hv.z, acc);
            acc = fmaf(wv.w, hv.w, acc);
        }
        rl[w][l] = fmaxf(acc, 0.0f);
    }
    __syncthreads();
    if (tid < NCH * 2) {
        const int c = tid >> 1;
        const int o = tid & 1;
        float acc = fc2_b[o];
        for (int k = 0; k < HID; ++k)
            acc = fmaf(fc2_w[o * HID + k], rl[c][k], acc);
        out[(size_t)(blk * NCH + c) * 2 + o] = acc;
    }
}

extern "C" void kernel_launch(void* const* d_in, const int* in_sizes, int n_in,
                              void* d_out, int out_size, void* d_ws, size_t ws_size,
                              hipStream_t stream) {
    const float* x     = (const float*)d_in[0];
    const float* W_ih  = (const float*)d_in[1];
    const float* W_hh  = (const float*)d_in[2];
    const float* b_ih  = (const float*)d_in[3];
    const float* b_hh  = (const float*)d_in[4];
    const float* fc1_w = (const float*)d_in[5];
    const float* fc1_b = (const float*)d_in[6];
    const float* fc2_w = (const float*)d_in[7];
    const float* fc2_b = (const float*)d_in[8];
    float* out = (float*)d_out;

    const int B = in_sizes[0] / (TSTEPS * IN_DIM);   // 1024
    lstm_mfma<<<B / NCH, 256, 0, stream>>>(x, W_ih, W_hh, b_ih, b_hh,
                                           fc1_w, fc1_b, fc2_w, fc2_b, out);
}